// Round 11
// baseline (255.240 us; speedup 1.0000x reference)
//
#include <hip/hip_runtime.h>
#include <hip/hip_bf16.h>

#define S_LEN 2048
#define BATCH 4
#define EMB   1024
#define NH    16
#define HD    64
#define NROW  8192

// 0.125 * log2(e): folded into Q projection so softmax exp is a bare v_exp_f32
#define QSCALE 0.18033688011112043f

typedef __bf16 bf16x8 __attribute__((ext_vector_type(8)));
typedef float  f32x4  __attribute__((ext_vector_type(4)));

typedef __attribute__((address_space(3))) void lds_void;
typedef const __attribute__((address_space(1))) void gbl_void;
#define GLOAD_LDS16(g, l) __builtin_amdgcn_global_load_lds((gbl_void*)(g), (lds_void*)(l), 16, 0, 0)
#define MFMA16(a, b, c) __builtin_amdgcn_mfma_f32_16x16x32_bf16((a), (b), (c), 0, 0, 0)

#if __has_builtin(__builtin_amdgcn_exp2f)
#define EXP2(x) __builtin_amdgcn_exp2f(x)
#else
#define EXP2(x) __expf((x) * 0.6931471805599453f)
#endif

// ---------------- fused fp32 -> bf16 conversion (x + 4 weights, 1 launch) --
__global__ void cvt_all_kernel(const float* __restrict__ x,
                               const float* __restrict__ wq, const float* __restrict__ wk,
                               const float* __restrict__ wv, const float* __restrict__ wo,
                               __bf16* __restrict__ xb,
                               __bf16* __restrict__ qb, __bf16* __restrict__ kb,
                               __bf16* __restrict__ vb, __bf16* __restrict__ ob) {
    const int bid = blockIdx.x;
    const float* src;
    __bf16* dst;
    int i;
    if (bid < 8192) {                       // x: 8192*1024/4 float4 = 8192 blocks
        src = x; dst = xb; i = bid * 256 + threadIdx.x;
    } else {                                // weights: 1024 blocks each
        const int w = (bid - 8192) >> 10;
        src = w == 0 ? wq : (w == 1 ? wk : (w == 2 ? wv : wo));
        dst = w == 0 ? qb : (w == 1 ? kb : (w == 2 ? vb : ob));
        i = ((bid - 8192) & 1023) * 256 + threadIdx.x;
    }
    float4 v = ((const float4*)src)[i];
    union { __bf16 h[4]; short4 s4; } u;
    u.h[0] = (__bf16)v.x; u.h[1] = (__bf16)v.y;
    u.h[2] = (__bf16)v.z; u.h[3] = (__bf16)v.w;
    ((short4*)dst)[i] = u.s4;
}

// One K-step of the 128x128 GEMM with COMPILE-TIME ring-buffer index BT.
// RACE FIX (r11): the pre-barrier wait now includes lgkmcnt(0) -- s_barrier
// does NOT drain lgkm, and hipcc may sink the MFMAs (register-only) below
// the barrier, so without it a wave can pass the barrier with last-iter
// ds_reads still queued while another wave's post-barrier global_load_lds
// overwrites that buffer (ring-3 reuse distance = 1 barrier).
#define GSTEP(C, BT, VM, DOSTAGE) do {                                        \
    asm volatile("s_waitcnt vmcnt(" VM ") lgkmcnt(0)" ::: "memory");          \
    __builtin_amdgcn_s_barrier();                                             \
    if (DOSTAGE) {                                                            \
        GLOAD_LDS16(gA0 + ((C) + 2) * 32, ldsA + (((BT) + 2) % 3) * 4096);    \
        GLOAD_LDS16(gA1 + ((C) + 2) * 32, ldsA + (((BT) + 2) % 3) * 4096 + 512); \
        GLOAD_LDS16(gW0 + ((C) + 2) * 32, ldsB + (((BT) + 2) % 3) * 4096);    \
        GLOAD_LDS16(gW1 + ((C) + 2) * 32, ldsB + (((BT) + 2) % 3) * 4096 + 512); \
    }                                                                         \
    bf16x8 af[4], bfr[4];                                                     \
    _Pragma("unroll")                                                         \
    for (int tt = 0; tt < 4; ++tt) {                                          \
        af[tt]  = *(const bf16x8*)(Ab + (BT) * 4096 + tt * 512);              \
        bfr[tt] = *(const bf16x8*)(Bb + (BT) * 4096 + tt * 512);              \
    }                                                                         \
    _Pragma("unroll")                                                         \
    for (int i = 0; i < 4; ++i)                                               \
        _Pragma("unroll")                                                     \
        for (int j = 0; j < 4; ++j)                                           \
            acc[i][j] = MFMA16(af[i], bfr[j], acc[i][j]);                     \
} while (0)

// One K-step of the 64x128 gemm_out tile: 3 staging loads (A:1, B:2),
// af[2] x bfr[4] -> 8 MFMAs. Same ring-3 discipline + same race fix.
#define GSTEP2(C, BT, VM, DOSTAGE) do {                                       \
    asm volatile("s_waitcnt vmcnt(" VM ") lgkmcnt(0)" ::: "memory");          \
    __builtin_amdgcn_s_barrier();                                             \
    if (DOSTAGE) {                                                            \
        GLOAD_LDS16(gA0 + ((C) + 2) * 32, ldsA + (((BT) + 2) % 3) * 2048);    \
        GLOAD_LDS16(gW0 + ((C) + 2) * 32, ldsB + (((BT) + 2) % 3) * 4096);    \
        GLOAD_LDS16(gW1 + ((C) + 2) * 32, ldsB + (((BT) + 2) % 3) * 4096 + 512); \
    }                                                                         \
    bf16x8 af[2], bfr[4];                                                     \
    _Pragma("unroll")                                                         \
    for (int tt = 0; tt < 2; ++tt)                                            \
        af[tt] = *(const bf16x8*)(Ab + (BT) * 2048 + tt * 512);               \
    _Pragma("unroll")                                                         \
    for (int tt = 0; tt < 4; ++tt)                                            \
        bfr[tt] = *(const bf16x8*)(Bb + (BT) * 4096 + tt * 512);              \
    _Pragma("unroll")                                                         \
    for (int i = 0; i < 2; ++i)                                               \
        _Pragma("unroll")                                                     \
        for (int j = 0; j < 4; ++j)                                           \
            acc[i][j] = MFMA16(af[i], bfr[j], acc[i][j]);                     \
} while (0)

// ---------------- fused QKV GEMM: 128x128 block tile ---------------------
__global__ __launch_bounds__(256) void gemm_qkv_kernel(
    const __bf16* __restrict__ A,
    const __bf16* __restrict__ W0, const __bf16* __restrict__ W1,
    const __bf16* __restrict__ W2,
    const float* __restrict__ bi0, const float* __restrict__ bi1,
    const float* __restrict__ bi2,
    __bf16* __restrict__ Qo, __bf16* __restrict__ Ko, __bf16* __restrict__ Vo)
{
    __shared__ __align__(16) char SMEM[49152];   // 3x(As 8KB) + 3x(Bs 8KB)
    __bf16* Asb = (__bf16*)SMEM;                 // [3][4096]
    __bf16* Bsb = (__bf16*)(SMEM + 24576);       // [3][4096]

    const int flat = blockIdx.x;            // 1536 = 8 xcd * 192
    const int xcd = flat & 7, slot = flat >> 3;
    const int nB = slot >> 3;               // 0..23 (nB-outer: W streams, A stays)
    const int mB = (xcd << 3) | (slot & 7); // 8 mB rows per XCD
    const int which = nB >> 3;
    const __bf16* W = which == 0 ? W0 : (which == 1 ? W1 : W2);
    const float* bias = which == 0 ? bi0 : (which == 1 ? bi1 : bi2);
    __bf16* outb = which == 0 ? Qo : (which == 1 ? Ko : Vo);
    const int m0 = mB * 128;
    const int n0 = (nB & 7) * 128;

    const int lane = threadIdx.x & 63;
    const int wave = threadIdx.x >> 6;
    const int l15 = lane & 15;
    const int quad = lane >> 4;
    const int wm = (wave >> 1) * 64;
    const int wn = (wave & 1) * 64;

    const int c0 = wave * 128 + lane;
    const int c1 = c0 + 64;
    // source chunk pre-swizzled: phys chunk c holds logical k-chunk (c&3)^((row>>1)&3)
    const int ar0 = c0 >> 2, ak0 = (((c0 & 3) ^ ((c0 >> 3) & 3))) * 8;
    const int ar1 = c1 >> 2, ak1 = (((c1 & 3) ^ ((c1 >> 3) & 3))) * 8;

    const __bf16* Ag = A + (size_t)m0 * EMB;
    const __bf16* Wg = W + (size_t)n0 * EMB;

    f32x4 acc[4][4];
#pragma unroll
    for (int i = 0; i < 4; ++i)
#pragma unroll
        for (int j = 0; j < 4; ++j) acc[i][j] = (f32x4){0.f, 0.f, 0.f, 0.f};

    // staging pointers (bumped 96 elems per 3-iter group) + LDS dests/bases
    const __bf16* gA0 = Ag + (size_t)ar0 * EMB + ak0;
    const __bf16* gA1 = Ag + (size_t)ar1 * EMB + ak1;
    const __bf16* gW0 = Wg + (size_t)ar0 * EMB + ak0;
    const __bf16* gW1 = Wg + (size_t)ar1 * EMB + ak1;
    __bf16* ldsA = Asb + wave * 1024;
    __bf16* ldsB = Bsb + wave * 1024;

    // prologue: t=0 -> buf0, t=1 -> buf1
    GLOAD_LDS16(gA0,      ldsA);
    GLOAD_LDS16(gA1,      ldsA + 512);
    GLOAD_LDS16(gW0,      ldsB);
    GLOAD_LDS16(gW1,      ldsB + 512);
    GLOAD_LDS16(gA0 + 32, ldsA + 4096);
    GLOAD_LDS16(gA1 + 32, ldsA + 4096 + 512);
    GLOAD_LDS16(gW0 + 32, ldsB + 4096);
    GLOAD_LDS16(gW1 + 32, ldsB + 4096 + 512);

    const int xr = (l15 >> 1) & 3;          // read-side chunk XOR
    const __bf16* Ab = Asb + (wm + l15) * 32 + ((quad ^ xr) << 3);
    const __bf16* Bb = Bsb + (wn + l15) * 32 + ((quad ^ xr) << 3);

    for (int g = 0; g < 10; ++g) {          // t = 3g .. 3g+2, buf = t%3
        GSTEP(0, 0, "4", 1);
        GSTEP(1, 1, "4", 1);
        GSTEP(2, 2, "4", 1);
        gA0 += 96; gA1 += 96; gW0 += 96; gW1 += 96;
    }
    GSTEP(0, 0, "4", 0);                    // t=30 (buf0), no stage
    GSTEP(1, 1, "0", 0);                    // t=31 (buf1), drain

    // ---- coalesced epilogue: wave-private LDS transpose, 16B stores ----
    __syncthreads();                         // all LDS reads of staging done
    __bf16* epi = (__bf16*)SMEM + wave * 2304;   // 32 rows x stride 72 = 4.5KB
    float bv[4];
#pragma unroll
    for (int j = 0; j < 4; ++j) bv[j] = bias[n0 + wn + j * 16 + l15];
    const int hh = (n0 + wn) >> 6;           // head index, constant per wave

    if (which != 2) {
        // Q/K layout: out[((b*NH+h)*S_LEN + s)*HD + d]; LDS[m_local][d]
#pragma unroll
        for (int p = 0; p < 2; ++p) {
#pragma unroll
            for (int ih = 0; ih < 2; ++ih) {
                const int i = 2 * p + ih;
#pragma unroll
                for (int j = 0; j < 4; ++j)
#pragma unroll
                    for (int r = 0; r < 4; ++r) {
                        float v = acc[i][j][r] + bv[j];
                        if (which == 0) v *= QSCALE;
                        epi[(ih * 16 + quad * 4 + r) * 72 + j * 16 + l15] = (__bf16)v;
                    }
            }
#pragma unroll
            for (int ii = 0; ii < 4; ++ii) {
                const int rl = ii * 8 + (lane >> 3);      // 0..31 within pass
                bf16x8 row = *(const bf16x8*)(epi + rl * 72 + (lane & 7) * 8);
                const int m = m0 + wm + p * 32 + rl;
                const int b = m & 3, s = m >> 2;
                *(bf16x8*)(outb + ((size_t)(b * NH + hh) * S_LEN + s) * HD
                           + (lane & 7) * 8) = row;
            }
            if (p == 0) __syncthreads();     // epi buffer reuse between passes
        }
    } else {
        // V layout: out[((b*NH+h)*HD + d)*S_LEN + s]; LDS[d_local][b*16+s_local]
        const int sb = (m0 + wm) >> 2;
#pragma unroll
        for (int p = 0; p < 2; ++p) {
#pragma unroll
            for (int jh = 0; jh < 2; ++jh) {
                const int j = 2 * p + jh;
#pragma unroll
                for (int i = 0; i < 4; ++i)
#pragma unroll
                    for (int r = 0; r < 4; ++r) {
                        float v = acc[i][j][r] + bv[j];
                        epi[(jh * 16 + l15) * 72 + r * 16 + i * 4 + quad] = (__bf16)v;
                    }
            }
#pragma unroll
            for (int ii = 0; ii < 4; ++ii) {              // ii = batch b
                const int q = lane >> 1;                  // d_local 0..31
                bf16x8 row = *(const bf16x8*)(epi + q * 72 + ii * 16 + (lane & 1) * 8);
                const int d = p * 32 + q;
                *(bf16x8*)(outb + ((size_t)(ii * NH + hh) * HD + d) * S_LEN
                           + sb + (lane & 1) * 8) = row;
            }
            if (p == 0) __syncthreads();     // epi buffer reuse between passes
        }
    }
}

// ---------------- output projection GEMM (fp32 out) ----------------------
// Retiled 64x128 (r10): grid 1024 blocks, LDS 36KB -> 4 blocks/CU =
// 16 waves/CU. XCD swizzle: 16 consecutive m-tiles per XCD.
__global__ __launch_bounds__(256) void gemm_out_kernel(
    const __bf16* __restrict__ A, const __bf16* __restrict__ W,
    const float* __restrict__ bias, float* __restrict__ outf)
{
    __shared__ __align__(16) char SMEM[36864];   // 3x(As 4KB) + 3x(Bs 8KB)
    __bf16* Asb = (__bf16*)SMEM;                 // [3][2048]
    __bf16* Bsb = (__bf16*)(SMEM + 12288);       // [3][4096]

    const int tid = threadIdx.x;
    const int flat = blockIdx.x;            // 1024 = 8 xcd * 128
    const int xcd = flat & 7, slot = flat >> 3;
    const int nB = slot >> 4;               // 0..7
    const int mB = (xcd << 4) | (slot & 15);// 0..127
    const int m0 = mB * 64;
    const int n0 = nB * 128;

    const int lane = tid & 63;
    const int wave = tid >> 6;
    const int l15 = lane & 15;
    const int quad = lane >> 4;
    const int wm = (wave >> 1) * 32;        // wave tile 32x64
    const int wn = (wave & 1) * 64;

    // A staging: 256 chunks (64 rows x 4 k-chunks), 1 GLOAD/thread
    const int ar = tid >> 2, aak = (((tid & 3) ^ ((tid >> 3) & 3))) * 8;
    // B staging: 512 chunks (128 rows x 4 k-chunks), 2 GLOADs/thread
    const int c0 = wave * 128 + lane;
    const int c1 = c0 + 64;
    const int br0 = c0 >> 2, bk0 = (((c0 & 3) ^ ((c0 >> 3) & 3))) * 8;
    const int br1 = c1 >> 2, bk1 = (((c1 & 3) ^ ((c1 >> 3) & 3))) * 8;

    const __bf16* gA0 = A + (size_t)(m0 + ar) * EMB + aak;
    const __bf16* gW0 = W + (size_t)(n0 + br0) * EMB + bk0;
    const __bf16* gW1 = W + (size_t)(n0 + br1) * EMB + bk1;
    __bf16* ldsA = Asb + wave * 512;
    __bf16* ldsB = Bsb + wave * 1024;

    f32x4 acc[2][4];
#pragma unroll
    for (int i = 0; i < 2; ++i)
#pragma unroll
        for (int j = 0; j < 4; ++j) acc[i][j] = (f32x4){0.f, 0.f, 0.f, 0.f};

    // prologue: tile 0 then tile 1 (tile-grouped issue order for vmcnt)
    GLOAD_LDS16(gA0,      ldsA);
    GLOAD_LDS16(gW0,      ldsB);
    GLOAD_LDS16(gW1,      ldsB + 512);
    GLOAD_LDS16(gA0 + 32, ldsA + 2048);
    GLOAD_LDS16(gW0 + 32, ldsB + 4096);
    GLOAD_LDS16(gW1 + 32, ldsB + 4096 + 512);

    const int xr = (l15 >> 1) & 3;
    const __bf16* Ab = Asb + (wm + l15) * 32 + ((quad ^ xr) << 3);
    const __bf16* Bb = Bsb + (wn + l15) * 32 + ((quad ^ xr) << 3);

    for (int g = 0; g < 10; ++g) {          // t = 3g .. 3g+2, buf = t%3
        GSTEP2(0, 0, "3", 1);
        GSTEP2(1, 1, "3", 1);
        GSTEP2(2, 2, "3", 1);
        gA0 += 96; gW0 += 96; gW1 += 96;
    }
    GSTEP2(0, 0, "3", 0);                   // t=30 (buf0), no stage
    GSTEP2(1, 1, "0", 0);                   // t=31 (buf1), drain

#pragma unroll
    for (int j = 0; j < 4; ++j) {
        const int col = n0 + wn + j * 16 + l15;
        const float bv = bias[col];
#pragma unroll
        for (int i = 0; i < 2; ++i)
#pragma unroll
            for (int r = 0; r < 4; ++r) {
                const int m = m0 + wm + i * 16 + quad * 4 + r;
                outf[(size_t)m * EMB + col] = acc[i][j][r] + bv;
            }
    }
}

// ---------------- Flash attention v9: in-reg P + early V + setprio --------
// r11: pre-barrier wait gains lgkmcnt(0) (same ring-3 reuse race class).
__global__ __launch_bounds__(256, 4) void attn_kernel(
    const __bf16* __restrict__ Q, const __bf16* __restrict__ Kp,
    const __bf16* __restrict__ Vt, __bf16* __restrict__ Ao)
{
    __shared__ __align__(16) __bf16 Ks[3][32 * 64];   // [t][d swizzled] 4KB ea
    __shared__ __align__(16) __bf16 Vs[3][32 * 64];   // [d][t swizzled] 4KB ea

    const int tid = threadIdx.x;
    const int lane = tid & 63;
    const int wave = tid >> 6;
    const int l15 = lane & 15;
    const int quad = lane >> 4;

    const int flat = blockIdx.y * gridDim.x + blockIdx.x;   // 1024 = 8 xcd * 128
    const int nf = (flat & 7) * 128 + (flat >> 3);
    const int bh = nf >> 4;
    const int b = bh >> 4, h = bh & 15;
    const int qw = (nf & 15) * 128 + wave * 32;

    const __bf16* Qb = Q  + (size_t)bh * S_LEN * HD;
    const __bf16* Kb = Kp + (size_t)bh * S_LEN * HD;
    const __bf16* Vb = Vt + (size_t)bh * HD * S_LEN;

    // K staging: 256 chunks (32 t-rows x 8 d-chunks); x(row)=(row&3)|((row>>3&1)<<2)
    const int kr = tid >> 3;
    const int ks = ((tid & 7) ^ ((kr & 3) | (((kr >> 3) & 1) << 2))) * 8;
    // V staging: 256 chunks (64 d-rows x 4 t-chunks), x = (row>>1)&3 (unchanged)
    const int vr = tid >> 2;
    const int vs = (((tid & 3) ^ ((tid >> 3) & 3))) * 8;

    bf16x8 qf[2][2];
#pragma unroll
    for (int mi = 0; mi < 2; ++mi)
#pragma unroll
        for (int kc = 0; kc < 2; ++kc)
            qf[mi][kc] = *(const bf16x8*)(Qb + (size_t)(qw + mi * 16 + l15) * HD
                                          + kc * 32 + quad * 8);

    bf16x8 ones;
#pragma unroll
    for (int i = 0; i < 8; ++i) ones[i] = (__bf16)1.0f;

    f32x4 acco[2][4], accl[2];
#pragma unroll
    for (int mi = 0; mi < 2; ++mi) {
        accl[mi] = (f32x4){0.f, 0.f, 0.f, 0.f};
#pragma unroll
        for (int nt = 0; nt < 4; ++nt) acco[mi][nt] = (f32x4){0.f, 0.f, 0.f, 0.f};
    }

    auto stageKV = [&](int t) {
        const int t0 = t * 32;
        GLOAD_LDS16(Kb + (size_t)(t0 + kr) * HD + ks, &Ks[t % 3][wave * 512]);
        GLOAD_LDS16(Vb + (size_t)vr * S_LEN + t0 + vs, &Vs[t % 3][wave * 512]);
    };
    stageKV(0);
    stageKV(1);

    // A-frag K-row for this lane: MFMA-A covers t=8*(l15>>2)+(l15&3), MFMA-B +4.
    const int ta = 8 * (l15 >> 2) + (l15 & 3);
    const int xk = (l15 & 3) | (((l15 >> 2) & 1) << 2);   // x(ta) == x(ta+4)
    const int xv = (l15 >> 1) & 3;                        // V read XOR (unchanged)

    for (int it = 0; it < S_LEN / 32; ++it) {
        if (it < S_LEN / 32 - 1) asm volatile("s_waitcnt vmcnt(2) lgkmcnt(0)" ::: "memory");
        else                     asm volatile("s_waitcnt vmcnt(0) lgkmcnt(0)" ::: "memory");
        __builtin_amdgcn_s_barrier();
        if (it + 2 < S_LEN / 32) stageKV(it + 2);

        const __bf16* Kt = &Ks[it % 3][0];
        const __bf16* Vl = &Vs[it % 3][0];

        // all LDS reads up front: K frags for QK, V frags for PV (latency of
        // the V reads hides under QK MFMAs + exp)
        bf16x8 kfA[2], kfB[2], vf[4];
#pragma unroll
        for (int kc = 0; kc < 2; ++kc) {
            kfA[kc] = *(const bf16x8*)(Kt + ta * 64 + (((kc * 4 + quad) ^ xk) << 3));
            kfB[kc] = *(const bf16x8*)(Kt + (ta + 4) * 64 + (((kc * 4 + quad) ^ xk) << 3));
        }
#pragma unroll
        for (int nt = 0; nt < 4; ++nt)
            vf[nt] = *(const bf16x8*)(Vl + (nt * 16 + l15) * 32 + ((quad ^ xv) << 3));

        // swapped QK^T: sA rows -> t=8*quad+r, sB rows -> t=8*quad+4+r
        bf16x8 pf[2];
#pragma unroll
        for (int mi = 0; mi < 2; ++mi) {
            f32x4 sA = {0.f, 0.f, 0.f, 0.f}, sB = {0.f, 0.f, 0.f, 0.f};
            __builtin_amdgcn_s_setprio(1);
            sA = MFMA16(kfA[0], qf[mi][0], sA);
            sA = MFMA16(kfA[1], qf[mi][1], sA);
            sB = MFMA16(kfB[0], qf[mi][0], sB);
            sB = MFMA16(kfB[1], qf[mi][1], sB);
            __builtin_amdgcn_s_setprio(0);
            // exp + pack in-register: pf element i holds P[q][t=8*quad+i]
            union { __bf16 hh[8]; bf16x8 v; } u;
#pragma unroll
            for (int r = 0; r < 4; ++r) {
                u.hh[r]     = (__bf16)EXP2(sA[r]);
                u.hh[4 + r] = (__bf16)EXP2(sB[r]);
            }
            pf[mi] = u.v;
        }
        // lsum + PV (pure MFMA cluster)
        __builtin_amdgcn_s_setprio(1);
#pragma unroll
        for (int mi = 0; mi < 2; ++mi)
            accl[mi] = MFMA16(pf[mi], ones, accl[mi]);
#pragma unroll
        for (int nt = 0; nt < 4; ++nt)
#pragma unroll
            for (int mi = 0; mi < 2; ++mi)
                acco[mi][nt] = MFMA16(pf[mi], vf[nt], acco[mi][nt]);
        __builtin_amdgcn_s_setprio(0);
    }

    // normalize: accl rows (quad*4+r) match acco rows exactly; no reduce needed
#pragma unroll
    for (int mi = 0; mi < 2; ++mi)
#pragma unroll
        for (int r = 0; r < 4; ++r) {
            const float inv = 1.0f / accl[mi][r];
            const int srow = qw + mi * 16 + quad * 4 + r;
            const int n = srow * BATCH + b;
#pragma unroll
            for (int nt = 0; nt < 4; ++nt)
                Ao[(size_t)n * EMB + h * 64 + nt * 16 + l15] =
                    (__bf16)(acco[mi][nt][r] * inv);
        }
}

// ---------------- host launch ----------------
extern "C" void kernel_launch(void* const* d_in, const int* in_sizes, int n_in,
                              void* d_out, int out_size, void* d_ws, size_t ws_size,
                              hipStream_t stream) {
    const float* x  = (const float*)d_in[0];
    const float* Wq = (const float*)d_in[1];
    const float* bq = (const float*)d_in[2];
    const float* Wk = (const float*)d_in[3];
    const float* bk = (const float*)d_in[4];
    const float* Wv = (const float*)d_in[5];
    const float* bv = (const float*)d_in[6];
    const float* Wo = (const float*)d_in[7];
    const float* bo = (const float*)d_in[8];
    float* out = (float*)d_out;

    char* ws = (char*)d_ws;
    const size_t xbf_sz = (size_t)NROW * EMB * 2;
    const size_t wbf_sz = (size_t)EMB * EMB * 2;
    const size_t qkv_sz = (size_t)BATCH * NH * S_LEN * HD * 2;
    __bf16* x_bf  = (__bf16*)ws;  ws += xbf_sz;
    __bf16* Wq_bf = (__bf16*)ws;  ws += wbf_sz;
    __bf16* Wk_bf = (__bf16*)ws;  ws += wbf_sz;
    __bf16* Wv_bf = (__bf16*)ws;  ws += wbf_sz;
    __bf16* Wo_bf = (__bf16*)ws;  ws += wbf_sz;
    __bf16* Qb    = (__bf16*)ws;  ws += qkv_sz;
    __bf16* Kb    = (__bf16*)ws;  ws += qkv_sz;
    __bf16* Vtb   = (__bf16*)ws;  ws += qkv_sz;
    __bf16* Aob   = (__bf16*)ws;  ws += qkv_sz;

    // x: 8192 blocks, 4 weights: 1024 blocks each
    cvt_all_kernel<<<8192 + 4 * 1024, 256, 0, stream>>>(
        x, Wq, Wk, Wv, Wo, x_bf, Wq_bf, Wk_bf, Wv_bf, Wo_bf);

    gemm_qkv_kernel<<<64 * 24, 256, 0, stream>>>(x_bf, Wq_bf, Wk_bf, Wv_bf,
                                                 bq, bk, bv, Qb, Kb, Vtb);
    dim3 ag(S_LEN / 128, BATCH * NH);
    attn_kernel<<<ag, 256, 0, stream>>>(Qb, Kb, Vtb, Aob);
    gemm_out_kernel<<<1024, 256, 0, stream>>>(Aob, Wo_bf, bo, out);
}

// Round 13
// 254.919 us; speedup vs baseline: 1.0013x; 1.0013x over previous
//
#include <hip/hip_runtime.h>
#include <hip/hip_bf16.h>

#define S_LEN 2048
#define BATCH 4
#define EMB   1024
#define NH    16
#define HD    64
#define NROW  8192

// 0.125 * log2(e): folded into Q projection so softmax exp is a bare v_exp_f32
#define QSCALE 0.18033688011112043f

typedef __bf16 bf16x8 __attribute__((ext_vector_type(8)));
typedef float  f32x4  __attribute__((ext_vector_type(4)));

typedef __attribute__((address_space(3))) void lds_void;
typedef const __attribute__((address_space(1))) void gbl_void;
#define GLOAD_LDS16(g, l) __builtin_amdgcn_global_load_lds((gbl_void*)(g), (lds_void*)(l), 16, 0, 0)
#define MFMA16(a, b, c) __builtin_amdgcn_mfma_f32_16x16x32_bf16((a), (b), (c), 0, 0, 0)

#if __has_builtin(__builtin_amdgcn_exp2f)
#define EXP2(x) __builtin_amdgcn_exp2f(x)
#else
#define EXP2(x) __expf((x) * 0.6931471805599453f)
#endif

// ---------------- fused fp32 -> bf16 conversion (x + 4 weights, 1 launch) --
__global__ void cvt_all_kernel(const float* __restrict__ x,
                               const float* __restrict__ wq, const float* __restrict__ wk,
                               const float* __restrict__ wv, const float* __restrict__ wo,
                               __bf16* __restrict__ xb,
                               __bf16* __restrict__ qb, __bf16* __restrict__ kb,
                               __bf16* __restrict__ vb, __bf16* __restrict__ ob) {
    const int bid = blockIdx.x;
    const float* src;
    __bf16* dst;
    int i;
    if (bid < 8192) {                       // x: 8192*1024/4 float4 = 8192 blocks
        src = x; dst = xb; i = bid * 256 + threadIdx.x;
    } else {                                // weights: 1024 blocks each
        const int w = (bid - 8192) >> 10;
        src = w == 0 ? wq : (w == 1 ? wk : (w == 2 ? wv : wo));
        dst = w == 0 ? qb : (w == 1 ? kb : (w == 2 ? vb : ob));
        i = ((bid - 8192) & 1023) * 256 + threadIdx.x;
    }
    float4 v = ((const float4*)src)[i];
    union { __bf16 h[4]; short4 s4; } u;
    u.h[0] = (__bf16)v.x; u.h[1] = (__bf16)v.y;
    u.h[2] = (__bf16)v.z; u.h[3] = (__bf16)v.w;
    ((short4*)dst)[i] = u.s4;
}

// One K-step of the 128x128 GEMM with COMPILE-TIME ring-buffer index BT.
// Pre-barrier wait includes lgkmcnt(0): s_barrier does NOT drain lgkm, and
// hipcc may sink register-only MFMAs below the barrier (r10 race, fixed r11).
#define GSTEP(C, BT, VM, DOSTAGE) do {                                        \
    asm volatile("s_waitcnt vmcnt(" VM ") lgkmcnt(0)" ::: "memory");          \
    __builtin_amdgcn_s_barrier();                                             \
    if (DOSTAGE) {                                                            \
        GLOAD_LDS16(gA0 + ((C) + 2) * 32, ldsA + (((BT) + 2) % 3) * 4096);    \
        GLOAD_LDS16(gA1 + ((C) + 2) * 32, ldsA + (((BT) + 2) % 3) * 4096 + 512); \
        GLOAD_LDS16(gW0 + ((C) + 2) * 32, ldsB + (((BT) + 2) % 3) * 4096);    \
        GLOAD_LDS16(gW1 + ((C) + 2) * 32, ldsB + (((BT) + 2) % 3) * 4096 + 512); \
    }                                                                         \
    bf16x8 af[4], bfr[4];                                                     \
    _Pragma("unroll")                                                         \
    for (int tt = 0; tt < 4; ++tt) {                                          \
        af[tt]  = *(const bf16x8*)(Ab + (BT) * 4096 + tt * 512);              \
        bfr[tt] = *(const bf16x8*)(Bb + (BT) * 4096 + tt * 512);              \
    }                                                                         \
    _Pragma("unroll")                                                         \
    for (int i = 0; i < 4; ++i)                                               \
        _Pragma("unroll")                                                     \
        for (int j = 0; j < 4; ++j)                                           \
            acc[i][j] = MFMA16(af[i], bfr[j], acc[i][j]);                     \
} while (0)

// One K-step of the 64x128 gemm_out tile: 3 staging loads (A:1, B:2),
// af[2] x bfr[4] -> 8 MFMAs. Same ring-3 discipline + same race fix.
#define GSTEP2(C, BT, VM, DOSTAGE) do {                                       \
    asm volatile("s_waitcnt vmcnt(" VM ") lgkmcnt(0)" ::: "memory");          \
    __builtin_amdgcn_s_barrier();                                             \
    if (DOSTAGE) {                                                            \
        GLOAD_LDS16(gA0 + ((C) + 2) * 32, ldsA + (((BT) + 2) % 3) * 2048);    \
        GLOAD_LDS16(gW0 + ((C) + 2) * 32, ldsB + (((BT) + 2) % 3) * 4096);    \
        GLOAD_LDS16(gW1 + ((C) + 2) * 32, ldsB + (((BT) + 2) % 3) * 4096 + 512); \
    }                                                                         \
    bf16x8 af[2], bfr[4];                                                     \
    _Pragma("unroll")                                                         \
    for (int tt = 0; tt < 2; ++tt)                                            \
        af[tt] = *(const bf16x8*)(Ab + (BT) * 2048 + tt * 512);               \
    _Pragma("unroll")                                                         \
    for (int tt = 0; tt < 4; ++tt)                                            \
        bfr[tt] = *(const bf16x8*)(Bb + (BT) * 4096 + tt * 512);              \
    _Pragma("unroll")                                                         \
    for (int i = 0; i < 2; ++i)                                               \
        _Pragma("unroll")                                                     \
        for (int j = 0; j < 4; ++j)                                           \
            acc[i][j] = MFMA16(af[i], bfr[j], acc[i][j]);                     \
} while (0)

// ---------------- fused QKV GEMM: 128x128 block tile (unchanged r11) ------
__global__ __launch_bounds__(256) void gemm_qkv_kernel(
    const __bf16* __restrict__ A,
    const __bf16* __restrict__ W0, const __bf16* __restrict__ W1,
    const __bf16* __restrict__ W2,
    const float* __restrict__ bi0, const float* __restrict__ bi1,
    const float* __restrict__ bi2,
    __bf16* __restrict__ Qo, __bf16* __restrict__ Ko, __bf16* __restrict__ Vo)
{
    __shared__ __align__(16) char SMEM[49152];   // 3x(As 8KB) + 3x(Bs 8KB)
    __bf16* Asb = (__bf16*)SMEM;                 // [3][4096]
    __bf16* Bsb = (__bf16*)(SMEM + 24576);       // [3][4096]

    const int flat = blockIdx.x;            // 1536 = 8 xcd * 192
    const int xcd = flat & 7, slot = flat >> 3;
    const int nB = slot >> 3;               // 0..23 (nB-outer: W streams, A stays)
    const int mB = (xcd << 3) | (slot & 7); // 8 mB rows per XCD
    const int which = nB >> 3;
    const __bf16* W = which == 0 ? W0 : (which == 1 ? W1 : W2);
    const float* bias = which == 0 ? bi0 : (which == 1 ? bi1 : bi2);
    __bf16* outb = which == 0 ? Qo : (which == 1 ? Ko : Vo);
    const int m0 = mB * 128;
    const int n0 = (nB & 7) * 128;

    const int lane = threadIdx.x & 63;
    const int wave = threadIdx.x >> 6;
    const int l15 = lane & 15;
    const int quad = lane >> 4;
    const int wm = (wave >> 1) * 64;
    const int wn = (wave & 1) * 64;

    const int c0 = wave * 128 + lane;
    const int c1 = c0 + 64;
    // source chunk pre-swizzled: phys chunk c holds logical k-chunk (c&3)^((row>>1)&3)
    const int ar0 = c0 >> 2, ak0 = (((c0 & 3) ^ ((c0 >> 3) & 3))) * 8;
    const int ar1 = c1 >> 2, ak1 = (((c1 & 3) ^ ((c1 >> 3) & 3))) * 8;

    const __bf16* Ag = A + (size_t)m0 * EMB;
    const __bf16* Wg = W + (size_t)n0 * EMB;

    f32x4 acc[4][4];
#pragma unroll
    for (int i = 0; i < 4; ++i)
#pragma unroll
        for (int j = 0; j < 4; ++j) acc[i][j] = (f32x4){0.f, 0.f, 0.f, 0.f};

    // staging pointers (bumped 96 elems per 3-iter group) + LDS dests/bases
    const __bf16* gA0 = Ag + (size_t)ar0 * EMB + ak0;
    const __bf16* gA1 = Ag + (size_t)ar1 * EMB + ak1;
    const __bf16* gW0 = Wg + (size_t)ar0 * EMB + ak0;
    const __bf16* gW1 = Wg + (size_t)ar1 * EMB + ak1;
    __bf16* ldsA = Asb + wave * 1024;
    __bf16* ldsB = Bsb + wave * 1024;

    // prologue: t=0 -> buf0, t=1 -> buf1
    GLOAD_LDS16(gA0,      ldsA);
    GLOAD_LDS16(gA1,      ldsA + 512);
    GLOAD_LDS16(gW0,      ldsB);
    GLOAD_LDS16(gW1,      ldsB + 512);
    GLOAD_LDS16(gA0 + 32, ldsA + 4096);
    GLOAD_LDS16(gA1 + 32, ldsA + 4096 + 512);
    GLOAD_LDS16(gW0 + 32, ldsB + 4096);
    GLOAD_LDS16(gW1 + 32, ldsB + 4096 + 512);

    const int xr = (l15 >> 1) & 3;          // read-side chunk XOR
    const __bf16* Ab = Asb + (wm + l15) * 32 + ((quad ^ xr) << 3);
    const __bf16* Bb = Bsb + (wn + l15) * 32 + ((quad ^ xr) << 3);

    for (int g = 0; g < 10; ++g) {          // t = 3g .. 3g+2, buf = t%3
        GSTEP(0, 0, "4", 1);
        GSTEP(1, 1, "4", 1);
        GSTEP(2, 2, "4", 1);
        gA0 += 96; gA1 += 96; gW0 += 96; gW1 += 96;
    }
    GSTEP(0, 0, "4", 0);                    // t=30 (buf0), no stage
    GSTEP(1, 1, "0", 0);                    // t=31 (buf1), drain

    // ---- coalesced epilogue: wave-private LDS transpose, 16B stores ----
    __syncthreads();                         // all LDS reads of staging done
    __bf16* epi = (__bf16*)SMEM + wave * 2304;   // 32 rows x stride 72 = 4.5KB
    float bv[4];
#pragma unroll
    for (int j = 0; j < 4; ++j) bv[j] = bias[n0 + wn + j * 16 + l15];
    const int hh = (n0 + wn) >> 6;           // head index, constant per wave

    if (which != 2) {
        // Q/K layout: out[((b*NH+h)*S_LEN + s)*HD + d]; LDS[m_local][d]
#pragma unroll
        for (int p = 0; p < 2; ++p) {
#pragma unroll
            for (int ih = 0; ih < 2; ++ih) {
                const int i = 2 * p + ih;
#pragma unroll
                for (int j = 0; j < 4; ++j)
#pragma unroll
                    for (int r = 0; r < 4; ++r) {
                        float v = acc[i][j][r] + bv[j];
                        if (which == 0) v *= QSCALE;
                        epi[(ih * 16 + quad * 4 + r) * 72 + j * 16 + l15] = (__bf16)v;
                    }
            }
#pragma unroll
            for (int ii = 0; ii < 4; ++ii) {
                const int rl = ii * 8 + (lane >> 3);      // 0..31 within pass
                bf16x8 row = *(const bf16x8*)(epi + rl * 72 + (lane & 7) * 8);
                const int m = m0 + wm + p * 32 + rl;
                const int b = m & 3, s = m >> 2;
                *(bf16x8*)(outb + ((size_t)(b * NH + hh) * S_LEN + s) * HD
                           + (lane & 7) * 8) = row;
            }
            if (p == 0) __syncthreads();     // epi buffer reuse between passes
        }
    } else {
        // V layout: out[((b*NH+h)*HD + d)*S_LEN + s]; LDS[d_local][b*16+s_local]
        const int sb = (m0 + wm) >> 2;
#pragma unroll
        for (int p = 0; p < 2; ++p) {
#pragma unroll
            for (int jh = 0; jh < 2; ++jh) {
                const int j = 2 * p + jh;
#pragma unroll
                for (int i = 0; i < 4; ++i)
#pragma unroll
                    for (int r = 0; r < 4; ++r) {
                        float v = acc[i][j][r] + bv[j];
                        epi[(jh * 16 + l15) * 72 + r * 16 + i * 4 + quad] = (__bf16)v;
                    }
            }
#pragma unroll
            for (int ii = 0; ii < 4; ++ii) {              // ii = batch b
                const int q = lane >> 1;                  // d_local 0..31
                bf16x8 row = *(const bf16x8*)(epi + q * 72 + ii * 16 + (lane & 1) * 8);
                const int d = p * 32 + q;
                *(bf16x8*)(outb + ((size_t)(ii * NH + hh) * HD + d) * S_LEN
                           + sb + (lane & 1) * 8) = row;
            }
            if (p == 0) __syncthreads();     // epi buffer reuse between passes
        }
    }
}

// ---------------- output projection GEMM (fp32 out, unchanged r11) --------
__global__ __launch_bounds__(256) void gemm_out_kernel(
    const __bf16* __restrict__ A, const __bf16* __restrict__ W,
    const float* __restrict__ bias, float* __restrict__ outf)
{
    __shared__ __align__(16) char SMEM[36864];   // 3x(As 4KB) + 3x(Bs 8KB)
    __bf16* Asb = (__bf16*)SMEM;                 // [3][2048]
    __bf16* Bsb = (__bf16*)(SMEM + 12288);       // [3][4096]

    const int tid = threadIdx.x;
    const int flat = blockIdx.x;            // 1024 = 8 xcd * 128
    const int xcd = flat & 7, slot = flat >> 3;
    const int nB = slot >> 4;               // 0..7
    const int mB = (xcd << 4) | (slot & 15);// 0..127
    const int m0 = mB * 64;
    const int n0 = nB * 128;

    const int lane = tid & 63;
    const int wave = tid >> 6;
    const int l15 = lane & 15;
    const int quad = lane >> 4;
    const int wm = (wave >> 1) * 32;        // wave tile 32x64
    const int wn = (wave & 1) * 64;

    // A staging: 256 chunks (64 rows x 4 k-chunks), 1 GLOAD/thread
    const int ar = tid >> 2, aak = (((tid & 3) ^ ((tid >> 3) & 3))) * 8;
    // B staging: 512 chunks (128 rows x 4 k-chunks), 2 GLOADs/thread
    const int c0 = wave * 128 + lane;
    const int c1 = c0 + 64;
    const int br0 = c0 >> 2, bk0 = (((c0 & 3) ^ ((c0 >> 3) & 3))) * 8;
    const int br1 = c1 >> 2, bk1 = (((c1 & 3) ^ ((c1 >> 3) & 3))) * 8;

    const __bf16* gA0 = A + (size_t)(m0 + ar) * EMB + aak;
    const __bf16* gW0 = W + (size_t)(n0 + br0) * EMB + bk0;
    const __bf16* gW1 = W + (size_t)(n0 + br1) * EMB + bk1;
    __bf16* ldsA = Asb + wave * 512;
    __bf16* ldsB = Bsb + wave * 1024;

    f32x4 acc[2][4];
#pragma unroll
    for (int i = 0; i < 2; ++i)
#pragma unroll
        for (int j = 0; j < 4; ++j) acc[i][j] = (f32x4){0.f, 0.f, 0.f, 0.f};

    // prologue: tile 0 then tile 1 (tile-grouped issue order for vmcnt)
    GLOAD_LDS16(gA0,      ldsA);
    GLOAD_LDS16(gW0,      ldsB);
    GLOAD_LDS16(gW1,      ldsB + 512);
    GLOAD_LDS16(gA0 + 32, ldsA + 2048);
    GLOAD_LDS16(gW0 + 32, ldsB + 4096);
    GLOAD_LDS16(gW1 + 32, ldsB + 4096 + 512);

    const int xr = (l15 >> 1) & 3;
    const __bf16* Ab = Asb + (wm + l15) * 32 + ((quad ^ xr) << 3);
    const __bf16* Bb = Bsb + (wn + l15) * 32 + ((quad ^ xr) << 3);

    for (int g = 0; g < 10; ++g) {          // t = 3g .. 3g+2, buf = t%3
        GSTEP2(0, 0, "3", 1);
        GSTEP2(1, 1, "3", 1);
        GSTEP2(2, 2, "3", 1);
        gA0 += 96; gW0 += 96; gW1 += 96;
    }
    GSTEP2(0, 0, "3", 0);                   // t=30 (buf0), no stage
    GSTEP2(1, 1, "0", 0);                   // t=31 (buf1), drain

#pragma unroll
    for (int j = 0; j < 4; ++j) {
        const int col = n0 + wn + j * 16 + l15;
        const float bv = bias[col];
#pragma unroll
        for (int i = 0; i < 2; ++i)
#pragma unroll
            for (int r = 0; r < 4; ++r) {
                const int m = m0 + wm + i * 16 + quad * 4 + r;
                outf[(size_t)m * EMB + col] = acc[i][j][r] + bv;
            }
    }
}

// ---------------- Flash attention v10: Tc=64 super-tiles ------------------
// v9 (in-reg P, early V, setprio, lgkm fix) with the K/V tile doubled to 64
// t-rows stored as TWO stacked verbatim 32-row sub-tiles (identical layouts
// and swizzles to the verified r6-r11 kernel). Each super-iteration runs the
// proven half-body twice under ONE vmcnt+lgkm wait + ONE barrier: sync tax
// halves (64 -> 32 barriers). Ring-2 depth-1: stage(t+1 -> buf^1) after
// barrier t (buf^1 last read at t-1, ordered by lgkmcnt(0)+barrier);
// vmcnt(0) covers tile-t loads issued one (2x longer) iteration ago.
// LDS 32KB -> still 4 blocks/CU, grid 1024 fully resident.
__global__ __launch_bounds__(256, 4) void attn_kernel(
    const __bf16* __restrict__ Q, const __bf16* __restrict__ Kp,
    const __bf16* __restrict__ Vt, __bf16* __restrict__ Ao)
{
    __shared__ __align__(16) __bf16 Ks[2][2][32 * 64];  // [buf][t-half][32t][64d]
    __shared__ __align__(16) __bf16 Vs[2][2][32 * 64];  // [buf][t-half][64d][32t]

    const int tid = threadIdx.x;
    const int lane = tid & 63;
    const int wave = tid >> 6;
    const int l15 = lane & 15;
    const int quad = lane >> 4;

    const int flat = blockIdx.y * gridDim.x + blockIdx.x;   // 1024 = 8 xcd * 128
    const int nf = (flat & 7) * 128 + (flat >> 3);
    const int bh = nf >> 4;
    const int b = bh >> 4, h = bh & 15;
    const int qw = (nf & 15) * 128 + wave * 32;

    const __bf16* Qb = Q  + (size_t)bh * S_LEN * HD;
    const __bf16* Kb = Kp + (size_t)bh * S_LEN * HD;
    const __bf16* Vb = Vt + (size_t)bh * HD * S_LEN;

    // K staging (per 32-row sub-tile): x(row)=(row&3)|((row>>3&1)<<2)
    const int kr = tid >> 3;
    const int ks = ((tid & 7) ^ ((kr & 3) | (((kr >> 3) & 1) << 2))) * 8;
    // V staging (per sub-tile): 64 d-rows x 4 t-chunks, x = (row>>1)&3
    const int vr = tid >> 2;
    const int vs = (((tid & 3) ^ ((tid >> 3) & 3))) * 8;

    bf16x8 qf[2][2];
#pragma unroll
    for (int mi = 0; mi < 2; ++mi)
#pragma unroll
        for (int kc = 0; kc < 2; ++kc)
            qf[mi][kc] = *(const bf16x8*)(Qb + (size_t)(qw + mi * 16 + l15) * HD
                                          + kc * 32 + quad * 8);

    bf16x8 ones;
#pragma unroll
    for (int i = 0; i < 8; ++i) ones[i] = (__bf16)1.0f;

    f32x4 acco[2][4], accl[2];
#pragma unroll
    for (int mi = 0; mi < 2; ++mi) {
        accl[mi] = (f32x4){0.f, 0.f, 0.f, 0.f};
#pragma unroll
        for (int nt = 0; nt < 4; ++nt) acco[mi][nt] = (f32x4){0.f, 0.f, 0.f, 0.f};
    }

    auto stageKV = [&](int t) {             // t indexes 64-row super-tiles
        const int t0 = t * 64;
        const int buf = t & 1;
        GLOAD_LDS16(Kb + (size_t)(t0 + kr) * HD + ks,       &Ks[buf][0][wave * 512]);
        GLOAD_LDS16(Kb + (size_t)(t0 + 32 + kr) * HD + ks,  &Ks[buf][1][wave * 512]);
        GLOAD_LDS16(Vb + (size_t)vr * S_LEN + t0 + vs,      &Vs[buf][0][wave * 512]);
        GLOAD_LDS16(Vb + (size_t)vr * S_LEN + t0 + 32 + vs, &Vs[buf][1][wave * 512]);
    };
    stageKV(0);

    // A-frag K-row for this lane: MFMA-A covers t=8*(l15>>2)+(l15&3), MFMA-B +4.
    const int ta = 8 * (l15 >> 2) + (l15 & 3);
    const int xk = (l15 & 3) | (((l15 >> 2) & 1) << 2);   // x(ta) == x(ta+4)
    const int xv = (l15 >> 1) & 3;                        // V read XOR

    for (int it = 0; it < S_LEN / 64; ++it) {
        asm volatile("s_waitcnt vmcnt(0) lgkmcnt(0)" ::: "memory");
        __builtin_amdgcn_s_barrier();
        if (it + 1 < S_LEN / 64) stageKV(it + 1);
        const int buf = it & 1;

#pragma unroll
        for (int th = 0; th < 2; ++th) {    // two verbatim 32-row half-bodies
            const __bf16* Kt = &Ks[buf][th][0];
            const __bf16* Vl = &Vs[buf][th][0];

            bf16x8 kfA[2], kfB[2], vf[4];
#pragma unroll
            for (int kc = 0; kc < 2; ++kc) {
                kfA[kc] = *(const bf16x8*)(Kt + ta * 64 + (((kc * 4 + quad) ^ xk) << 3));
                kfB[kc] = *(const bf16x8*)(Kt + (ta + 4) * 64 + (((kc * 4 + quad) ^ xk) << 3));
            }
#pragma unroll
            for (int nt = 0; nt < 4; ++nt)
                vf[nt] = *(const bf16x8*)(Vl + (nt * 16 + l15) * 32 + ((quad ^ xv) << 3));

            // swapped QK^T: sA rows -> t=8*quad+r, sB rows -> t=8*quad+4+r
            bf16x8 pf[2];
#pragma unroll
            for (int mi = 0; mi < 2; ++mi) {
                f32x4 sA = {0.f, 0.f, 0.f, 0.f}, sB = {0.f, 0.f, 0.f, 0.f};
                __builtin_amdgcn_s_setprio(1);
                sA = MFMA16(kfA[0], qf[mi][0], sA);
                sA = MFMA16(kfA[1], qf[mi][1], sA);
                sB = MFMA16(kfB[0], qf[mi][0], sB);
                sB = MFMA16(kfB[1], qf[mi][1], sB);
                __builtin_amdgcn_s_setprio(0);
                // exp + pack in-register: pf element i holds P[q][t=8*quad+i]
                union { __bf16 hh[8]; bf16x8 v; } u;
#pragma unroll
                for (int r = 0; r < 4; ++r) {
                    u.hh[r]     = (__bf16)EXP2(sA[r]);
                    u.hh[4 + r] = (__bf16)EXP2(sB[r]);
                }
                pf[mi] = u.v;
            }
            // lsum + PV (pure MFMA cluster)
            __builtin_amdgcn_s_setprio(1);
#pragma unroll
            for (int mi = 0; mi < 2; ++mi)
                accl[mi] = MFMA16(pf[mi], ones, accl[mi]);
#pragma unroll
            for (int nt = 0; nt < 4; ++nt)
#pragma unroll
                for (int mi = 0; mi < 2; ++mi)
                    acco[mi][nt] = MFMA16(pf[mi], vf[nt], acco[mi][nt]);
            __builtin_amdgcn_s_setprio(0);
        }
    }

    // normalize: accl rows (quad*4+r) match acco rows exactly; no reduce needed
#pragma unroll
    for (int mi = 0; mi < 2; ++mi)
#pragma unroll
        for (int r = 0; r < 4; ++r) {
            const float inv = 1.0f / accl[mi][r];
            const int srow = qw + mi * 16 + quad * 4 + r;
            const int n = srow * BATCH + b;
#pragma unroll
            for (int nt = 0; nt < 4; ++nt)
                Ao[(size_t)n * EMB + h * 64 + nt * 16 + l15] =
                    (__bf16)(acco[mi][nt][r] * inv);
        }
}

// ---------------- host launch ----------------
extern "C" void kernel_launch(void* const* d_in, const int* in_sizes, int n_in,
                              void* d_out, int out_size, void* d_ws, size_t ws_size,
                              hipStream_t stream) {
    const float* x  = (const float*)d_in[0];
    const float* Wq = (const float*)d_in[1];
    const float* bq = (const float*)d_in[2];
    const float* Wk = (const float*)d_in[3];
    const float* bk = (const float*)d_in[4];
    const float* Wv = (const float*)d_in[5];
    const float* bv = (const float*)d_in[6];
    const float* Wo = (const float*)d_in[7];
    const float* bo = (const float*)d_in[8];
    float* out = (float*)d_out;

    char* ws = (char*)d_ws;
    const size_t xbf_sz = (size_t)NROW * EMB * 2;
    const size_t wbf_sz = (size_t)EMB * EMB * 2;
    const size_t qkv_sz = (size_t)BATCH * NH * S_LEN * HD * 2;
    __bf16* x_bf  = (__bf16*)ws;  ws += xbf_sz;
    __bf16* Wq_bf = (__bf16*)ws;  ws += wbf_sz;
    __bf16* Wk_bf = (__bf16*)ws;  ws += wbf_sz;
    __bf16* Wv_bf = (__bf16*)ws;  ws += wbf_sz;
    __bf16* Wo_bf = (__bf16*)ws;  ws += wbf_sz;
    __bf16* Qb    = (__bf16*)ws;  ws += qkv_sz;
    __bf16* Kb    = (__bf16*)ws;  ws += qkv_sz;
    __bf16* Vtb   = (__bf16*)ws;  ws += qkv_sz;
    __bf16* Aob   = (__bf16*)ws;  ws += qkv_sz;

    // x: 8192 blocks, 4 weights: 1024 blocks each
    cvt_all_kernel<<<8192 + 4 * 1024, 256, 0, stream>>>(
        x, Wq, Wk, Wv, Wo, x_bf, Wq_bf, Wk_bf, Wv_bf, Wo_bf);

    gemm_qkv_kernel<<<64 * 24, 256, 0, stream>>>(x_bf, Wq_bf, Wk_bf, Wv_bf,
                                                 bq, bk, bv, Qb, Kb, Vtb);
    dim3 ag(S_LEN / 128, BATCH * NH);
    attn_kernel<<<ag, 256, 0, stream>>>(Qb, Kb, Vtb, Aob);
    gemm_out_kernel<<<1024, 256, 0, stream>>>(Aob, Wo_bf, bo, out);
}